// Round 4
// baseline (422.239 us; speedup 1.0000x reference)
//
#include <hip/hip_runtime.h>
#include <math.h>

#define CIN   32
#define COUT  32
#define KS    3
#define HH    256
#define WW    256
#define BB    16
#define SDIM  512

#define TILE        32   // spatial tile (32x32)
#define CO_PER_BLK  16
#define CHUNK       8    // ci channels staged in LDS per pass

// ---------------- prep: s = style @ (mod_weight*mscale)^T + bias ----------------
__global__ __launch_bounds__(512) void prep_s_kernel(
    const float* __restrict__ style,
    const float* __restrict__ mod_weight,
    const float* __restrict__ mod_bias,
    float* __restrict__ s_out) {
    int t = threadIdx.x;            // 512 threads, 1 block: t -> (b, ci)
    int b = t >> 5, ci = t & 31;
    const float mscale = 0.044194173824159216f;  // 1/sqrt(512)
    const float* st = style + b * SDIM;
    const float* mw = mod_weight + ci * SDIM;
    float acc = 0.f;
    for (int d = 0; d < SDIM; d += 4) {
        acc += st[d]   * mw[d]
             + st[d+1] * mw[d+1]
             + st[d+2] * mw[d+2]
             + st[d+3] * mw[d+3];
    }
    s_out[t] = acc * mscale + mod_bias[ci];
}

// ---------------- prep: wmod[b,co,ci,kh,kw] = wscale * weight * s[b,ci] ----------
__global__ __launch_bounds__(256) void prep_w_kernel(
    const float* __restrict__ weight,
    const float* __restrict__ s,
    float* __restrict__ wmod) {
    int idx = blockIdx.x * 256 + threadIdx.x;
    if (idx >= BB * COUT * CIN * KS * KS) return;
    const float wscale = 0.05892556509887896f;   // 1/sqrt(32*3*3)
    int b = idx / (COUT * CIN * KS * KS);
    int r = idx % (COUT * CIN * KS * KS);        // co*288 + ci*9 + k
    int q = r % (CIN * KS * KS);
    int ci = q / (KS * KS);
    wmod[idx] = wscale * weight[r] * s[b * CIN + ci];
}

// ---------------- main conv + partial stats ----------------
// grid: (64 tiles, 2 co-groups, 16 batch), 256 threads
// per thread: 4 cout x (4x4 px) = 64 fp32 accumulators
__global__ __launch_bounds__(256, 3) void conv_kernel(
    const float* __restrict__ input,
    const float* __restrict__ wmod,
    float* __restrict__ out,
    float2* __restrict__ partials) {

    __shared__ float in_lds[CHUNK][34][36];        // rows padded 34->36 (16B align)
    __shared__ float w_lds[CHUNK][CO_PER_BLK][12]; // 9 -> 12 pad (16B align)

    const int tid  = threadIdx.x;
    const int tile = blockIdx.x;       // 0..63
    const int cog  = blockIdx.y;       // 0..1
    const int b    = blockIdx.z;       // 0..15
    const int tx0 = (tile & 7) * TILE;
    const int ty0 = (tile >> 3) * TILE;
    const int co_base = cog * CO_PER_BLK;

    const int q   = tid & 63;
    const int qx  = q & 7, qy = q >> 3;     // 8x8 grid of 4x4 quads
    const int px0 = qx * 4, py0 = qy * 4;
    const int cop = tid >> 6;               // wave id 0..3 (uniform per wave)

    float acc[4][4][4];
    #pragma unroll
    for (int j = 0; j < 4; ++j)
        #pragma unroll
        for (int py = 0; py < 4; ++py)
            #pragma unroll
            for (int px = 0; px < 4; ++px) acc[j][py][px] = 0.f;

    for (int ci0 = 0; ci0 < CIN; ci0 += CHUNK) {
        // ---- stage input tile (with halo, zero-padded) ----
        for (int i = tid; i < CHUNK * 34 * 34; i += 256) {
            int ci8 = i / (34 * 34);
            int rr  = i % (34 * 34);
            int r = rr / 34, c = rr % 34;
            int gy = ty0 - 1 + r, gx = tx0 - 1 + c;
            float v = 0.f;
            if ((unsigned)gy < 256u && (unsigned)gx < 256u)
                v = input[(((b * CIN) + ci0 + ci8) * 256 + gy) * 256 + gx];
            in_lds[ci8][r][c] = v;
        }
        // ---- stage weights for this chunk ----
        for (int i = tid; i < CHUNK * CO_PER_BLK * 9; i += 256) {
            int co = i / 72;
            int r  = i % 72;
            int ci8 = r / 9, k = r % 9;
            w_lds[ci8][co][k] =
                wmod[((b * COUT) + co_base + co) * (CIN * 9) + (ci0 + ci8) * 9 + k];
        }
        __syncthreads();

        #pragma unroll 1
        for (int ci8 = 0; ci8 < CHUNK; ++ci8) {
            // load 6x6 input patch into registers (vectorized LDS reads)
            float xr[6][6];
            #pragma unroll
            for (int dy = 0; dy < 6; ++dy) {
                const float* rowp = &in_lds[ci8][py0 + dy][px0];
                float4 a  = *(const float4*)rowp;
                float2 c2 = *(const float2*)(rowp + 4);
                xr[dy][0] = a.x; xr[dy][1] = a.y; xr[dy][2] = a.z; xr[dy][3] = a.w;
                xr[dy][4] = c2.x; xr[dy][5] = c2.y;
            }
            #pragma unroll
            for (int j = 0; j < 4; ++j) {
                const float* wp = &w_lds[ci8][cop * 4 + j][0];
                float4 w0 = *(const float4*)wp;
                float4 w1 = *(const float4*)(wp + 4);
                float  w8 = wp[8];
                float wr[9] = {w0.x, w0.y, w0.z, w0.w, w1.x, w1.y, w1.z, w1.w, w8};
                #pragma unroll
                for (int kh = 0; kh < 3; ++kh)
                    #pragma unroll
                    for (int kw = 0; kw < 3; ++kw)
                        #pragma unroll
                        for (int py = 0; py < 4; ++py)
                            #pragma unroll
                            for (int px = 0; px < 4; ++px)
                                acc[j][py][px] = fmaf(wr[kh * 3 + kw],
                                                      xr[py + kh][px + kw],
                                                      acc[j][py][px]);
            }
        }
        __syncthreads();
    }

    // ---- write raw conv output + per-(b,co,tile) partial stats ----
    const int lane = tid & 63;
    #pragma unroll
    for (int j = 0; j < 4; ++j) {
        const int co = co_base + cop * 4 + j;
        float lsum = 0.f, lsq = 0.f;
        #pragma unroll
        for (int py = 0; py < 4; ++py) {
            #pragma unroll
            for (int px = 0; px < 4; ++px) {
                float v = acc[j][py][px];
                lsum += v;
                lsq  += v * v;
            }
            float4 v4 = make_float4(acc[j][py][0], acc[j][py][1],
                                    acc[j][py][2], acc[j][py][3]);
            *(float4*)&out[(((b * COUT) + co) * 256 + (ty0 + py0 + py)) * 256
                           + (tx0 + px0)] = v4;
        }
        // wave (64-lane) reduction, fixed order -> deterministic
        #pragma unroll
        for (int off = 32; off > 0; off >>= 1) {
            lsum += __shfl_xor(lsum, off);
            lsq  += __shfl_xor(lsq,  off);
        }
        if (lane == 0)
            partials[((b * COUT) + co) * 64 + tile] = make_float2(lsum, lsq);
    }
}

// ---------------- fold tile partials -> inv std ----------------
__global__ __launch_bounds__(256) void reduce_kernel(
    const float2* __restrict__ partials,
    float* __restrict__ inv_std) {
    int t = blockIdx.x * 256 + threadIdx.x;
    if (t >= BB * COUT) return;
    float s = 0.f, sq = 0.f;
    for (int k = 0; k < 64; ++k) {
        float2 p = partials[t * 64 + k];
        s += p.x; sq += p.y;
    }
    const float N = 65536.f;
    float var = (sq - s * s / N) / (N - 1.f);   // unbiased (ddof=1)
    inv_std[t] = 1.0f / sqrtf(var);
}

// ---------------- scale output in place ----------------
__global__ __launch_bounds__(256) void scale_kernel(
    float4* __restrict__ out,
    const float* __restrict__ inv_std) {
    const int n4 = BB * COUT * HH * WW / 4;     // 8388608
    for (int i = blockIdx.x * 256 + threadIdx.x; i < n4; i += gridDim.x * 256) {
        float m = inv_std[i >> 14];             // (i*4)>>16
        float4 v = out[i];
        v.x *= m; v.y *= m; v.z *= m; v.w *= m;
        out[i] = v;
    }
}

extern "C" void kernel_launch(void* const* d_in, const int* in_sizes, int n_in,
                              void* d_out, int out_size, void* d_ws, size_t ws_size,
                              hipStream_t stream) {
    const float* input      = (const float*)d_in[0];
    const float* style      = (const float*)d_in[1];
    const float* weight     = (const float*)d_in[2];
    const float* mod_weight = (const float*)d_in[3];
    const float* mod_bias   = (const float*)d_in[4];
    float* out = (float*)d_out;
    float* ws  = (float*)d_ws;

    float*  s        = ws;                       // 512 floats
    float*  wmod     = ws + 512;                 // 147456 floats
    float2* partials = (float2*)(ws + 147968);   // 32768 float2
    float*  inv      = ws + 213504;              // 512 floats

    prep_s_kernel<<<1, 512, 0, stream>>>(style, mod_weight, mod_bias, s);
    prep_w_kernel<<<(BB * COUT * CIN * KS * KS + 255) / 256, 256, 0, stream>>>(
        weight, s, wmod);

    dim3 grid(64, 2, BB);
    conv_kernel<<<grid, 256, 0, stream>>>(input, wmod, out, partials);

    reduce_kernel<<<2, 256, 0, stream>>>(partials, inv);
    scale_kernel<<<2048, 256, 0, stream>>>((float4*)out, inv);
}